// Round 12
// baseline (1235.208 us; speedup 1.0000x reference)
//
#include <hip/hip_runtime.h>
#include <hip/hip_cooperative_groups.h>
#include <cstdint>
#include <cstddef>

namespace cg = cooperative_groups;

#define N_NODES 16384
#define N_EDGES 65536
#define EN_TOT  (N_EDGES + N_NODES)
#define FIN 7
#define HC 1600
#define NH 8
#define CHD 200
#define GCN 1600
#define CNN 64
#define BATCH 16
#define BN_EPS 1e-5f

typedef unsigned short ushort_t;
typedef __attribute__((ext_vector_type(8))) short s8frag;
typedef __attribute__((ext_vector_type(4))) float f32x4;

__device__ __forceinline__ ushort_t f2bf(float f) {
    unsigned u = __float_as_uint(f);
    unsigned r = (u + 0x7FFFu + ((u >> 16) & 1u)) >> 16;
    return (ushort_t)r;
}
__device__ __forceinline__ float bf2f(ushort_t u) {
    return __uint_as_float(((unsigned)u) << 16);
}

__device__ __forceinline__ void gload16(const void* g, void* l) {
    __builtin_amdgcn_global_load_lds((const __attribute__((address_space(1))) void*)g,
                                     (__attribute__((address_space(3))) void*)l, 16, 0, 0);
}

#define SWZ_KOFF(tid) ((((tid) & 3) ^ (((tid) >> 3) & 3)) << 3)
#define SWZ_AQ(lane, am) (((((lane) >> 4) ^ (((am) >> 1) & 3)) << 3))

// ---------------------------------------------------------------- GAT prep
__global__ __launch_bounds__(256) void k_count(
    const int* __restrict__ dst, const float* __restrict__ ea,
    int* __restrict__ cnt, float* __restrict__ ea_sum)
{
    int e = blockIdx.x * 256 + threadIdx.x;
    int d = (e < N_EDGES) ? dst[e] : (e - N_EDGES);
    atomicAdd(&cnt[d], 1);
    float v = (e < N_EDGES) ? ea[e] : 0.f;
#pragma unroll
    for (int o = 1; o < 64; o <<= 1) v += __shfl_xor(v, o);
    if ((threadIdx.x & 63) == 0) atomicAdd(ea_sum, v);
}

__global__ __launch_bounds__(256) void k_scan(int* __restrict__ cnt, int* __restrict__ offs)
{
    __shared__ int part[256];
    int t = threadIdx.x;
    int base_i = t * 64;
    int s = 0;
    for (int i = 0; i < 64; i++) s += cnt[base_i + i];
    part[t] = s;
    __syncthreads();
    for (int o = 1; o < 256; o <<= 1) {
        int add = (t >= o) ? part[t - o] : 0;
        __syncthreads();
        part[t] += add;
        __syncthreads();
    }
    int run = (t == 0) ? 0 : part[t - 1];
    for (int i = 0; i < 64; i++) {
        int v = cnt[base_i + i];
        offs[base_i + i] = run;
        run += v;
        cnt[base_i + i] = 0;
    }
    if (t == 255) offs[N_NODES] = run;
}

__global__ __launch_bounds__(256) void k_fill(const int* __restrict__ dst,
    const int* __restrict__ offs, int* __restrict__ cur, int* __restrict__ eid)
{
    int e = blockIdx.x * 256 + threadIdx.x;
    if (e >= EN_TOT) return;
    int d = (e < N_EDGES) ? dst[e] : (e - N_EDGES);
    int pos = offs[d] + atomicAdd(&cur[d], 1);
    eid[pos] = e;
}

// ---------------------------------------------------------------- merged weight prep
__global__ __launch_bounds__(256) void k_prep(
    const float* __restrict__ W1, const float* __restrict__ W2, const float* __restrict__ Wp,
    const float* __restrict__ cw1, const float* __restrict__ cw2,
    const float* __restrict__ cw3, const float* __restrict__ cw4,
    const float* __restrict__ Wl, const float* __restrict__ bl,
    const float* __restrict__ Wr, const float* __restrict__ br,
    const float* __restrict__ We, const float* __restrict__ att,
    ushort_t* __restrict__ W1T, ushort_t* __restrict__ W2T, ushort_t* __restrict__ WpT,
    ushort_t* __restrict__ c1T, ushort_t* __restrict__ c2T,
    ushort_t* __restrict__ c3T, ushort_t* __restrict__ c4T,
    ushort_t* __restrict__ G, float* __restrict__ att16)
{
    __shared__ float t[32][33];
    int lb = blockIdx.x;
    int tid = threadIdx.x;
    if (lb < 5400) {
        // transpose stages: W1 (2600), W2 (2600), Wp (200)
        const float* W; ushort_t* BT; int Ndim, bx, by;
        if (lb < 2600)      { W = W1; BT = W1T; Ndim = 1600; bx = lb % 52; by = lb / 52; }
        else if (lb < 5200) { W = W2; BT = W2T; Ndim = 1600; int l = lb - 2600; bx = l % 52; by = l / 52; }
        else                { W = Wp; BT = WpT; Ndim = 64;   int l = lb - 5200; bx = l % 4;  by = l / 4; }
        int tx = tid & 31, ty = tid >> 5;
        int n0 = bx * 32, k0 = by * 32;
#pragma unroll
        for (int i = 0; i < 4; i++)
            t[ty + i * 8][tx] = (n0 + tx < Ndim)
                ? W[(size_t)(k0 + ty + i * 8) * Ndim + n0 + tx] : 0.f;
        __syncthreads();
#pragma unroll
        for (int i = 0; i < 4; i++)
            BT[(size_t)(n0 + ty + i * 8) * 1600 + k0 + tx] = f2bf(t[tx][ty + i * 8]);
    } else if (lb < 9400) {
        int idx = (lb - 5400) * 256 + tid;
        const int R1 = 128 * 1600, R2 = 128 * 1600, R3 = 128 * 3200;
        const float* w; ushort_t* o; int local, K, Cin, Cout;
        if (idx < R1)                { w = cw1; o = c1T; local = idx; K = 1600; Cin = 64;  Cout = 64; }
        else if (idx < R1 + R2)      { w = cw2; o = c2T; local = idx - R1; K = 1600; Cin = 64; Cout = 128; }
        else if (idx < R1 + R2 + R3) { w = cw3; o = c3T; local = idx - R1 - R2; K = 3200; Cin = 128; Cout = 64; }
        else                         { w = cw4; o = c4T; local = idx - R1 - R2 - R3; K = 1600; Cin = 64; Cout = 6; }
        int co = local / K;
        int k = local - co * K;
        int p = k / Cin, ci = k - p * Cin;
        o[local] = (co < Cout) ? f2bf(w[(size_t)(co * Cin + ci) * 25 + p]) : (ushort_t)0;
    } else {
        int cp = (lb - 9400) * 256 + tid;
        if (cp < 8 * 208) {
            int h = cp / 208, j = cp - h * 208;
            ushort_t v[32];
#pragma unroll
            for (int k = 0; k < 32; k++) v[k] = 0;
            float av = 0.f;
            if (j < 200) {
                int c = h * 200 + j;
#pragma unroll
                for (int k = 0; k < 7; k++) v[k]     = f2bf(Wl[k * HC + c]);
#pragma unroll
                for (int k = 0; k < 7; k++) v[7 + k] = f2bf(Wr[k * HC + c]);
                v[14] = f2bf(We[c]);
                v[15] = f2bf(bl[c] + br[c]);
                av = att[h * CHD + j];
            }
            uint4* dst4 = (uint4*)(G + (size_t)cp * 32);
#pragma unroll
            for (int i = 0; i < 4; i++) dst4[i] = ((uint4*)v)[i];
            att16[cp] = av;
        }
    }
}

// ---------------------------------------------------------------- MFMA alpha
__global__ __launch_bounds__(256) void k_alpha_mm(
    const float* __restrict__ x, const float* __restrict__ edge_attr,
    const float* __restrict__ ea_sum, const int* __restrict__ src,
    const int* __restrict__ dst, const ushort_t* __restrict__ G,
    const float* __restrict__ att16, float* __restrict__ alpha)
{
    __shared__ ushort_t Fs[64 * 32];
    int tid = threadIdx.x;
    int lane = tid & 63, w = tid >> 6;
    int e0 = blockIdx.x * 64;
    float eam = ea_sum[0] * (1.f / (float)N_EDGES);

#define FSLOT(j, k) ((j) * 32 + ((((k) >> 3) ^ (((j) >> 1) & 3)) << 3) + ((k) & 7))
    for (int i = tid; i < 64 * 16; i += 256) {
        int j = i >> 4, k = (i & 15) + 16;
        Fs[FSLOT(j, k)] = 0;
    }
    {
        int j = tid >> 2, part = tid & 3;
        int e = e0 + j;
        int s, d; float ea;
        if (e < N_EDGES) { s = src[e]; d = dst[e]; ea = edge_attr[e]; }
        else             { s = e - N_EDGES; d = s; ea = eam; }
        if (part == 0) {
#pragma unroll
            for (int k = 0; k < 4; k++) Fs[FSLOT(j, k)] = f2bf(x[s * 7 + k]);
        } else if (part == 1) {
#pragma unroll
            for (int k = 4; k < 7; k++) Fs[FSLOT(j, k)] = f2bf(x[s * 7 + k]);
            Fs[FSLOT(j, 7)] = f2bf(x[d * 7 + 0]);
        } else if (part == 2) {
#pragma unroll
            for (int k = 1; k < 5; k++) Fs[FSLOT(j, 7 + k)] = f2bf(x[d * 7 + k]);
        } else {
            Fs[FSLOT(j, 12)] = f2bf(x[d * 7 + 5]);
            Fs[FSLOT(j, 13)] = f2bf(x[d * 7 + 6]);
            Fs[FSLOT(j, 14)] = f2bf(ea);
            Fs[FSLOT(j, 15)] = f2bf(1.0f);
        }
    }
#undef FSLOT
    __syncthreads();

    int am = lane & 15;
    int aq = (lane >> 4) * 8;
    s8frag afrag = *(const s8frag*)&Fs[(w * 16 + am) * 32 + SWZ_AQ(lane, am)];
    int lr4 = (lane >> 4) * 4;
    int ew = e0 + w * 16;
#pragma unroll
    for (int h = 0; h < NH; h++) {
        f32x4 hacc = (f32x4)0.f;
        int colbase = h * 208;
#pragma unroll
        for (int t = 0; t < 13; t++) {
            int cb = colbase + t * 16;
            s8frag bfrag = *(const s8frag*)(G + ((size_t)(cb + am) * 32 + aq));
            f32x4 z = (f32x4)0.f;
            f32x4 p = __builtin_amdgcn_mfma_f32_16x16x32_bf16(afrag, bfrag, z, 0, 0, 0);
            float attv = att16[cb + am];
#pragma unroll
            for (int r = 0; r < 4; r++) {
                float v = p[r];
                v = (v >= 0.f) ? v : 0.2f * v;
                hacc[r] += v * attv;
            }
        }
#pragma unroll
        for (int o = 1; o <= 8; o <<= 1) {
#pragma unroll
            for (int r = 0; r < 4; r++) hacc[r] += __shfl_xor(hacc[r], o);
        }
        if (am == 0) {
#pragma unroll
            for (int r = 0; r < 4; r++)
                alpha[(size_t)(ew + lr4 + r) * NH + h] = hacc[r];
        }
    }
}

// ---------------------------------------------------------------- softmax + 7-dim aggregation
__global__ __launch_bounds__(256) void k_agg_x(
    const float* __restrict__ x, const float* __restrict__ alpha,
    const int* __restrict__ offs, const int* __restrict__ eid,
    const int* __restrict__ src, float* __restrict__ xbar)
{
    int n = blockIdx.x * 4 + (threadIdx.x >> 6);
    int lane = threadIdx.x & 63;
    int beg = offs[n], deg = offs[n + 1] - beg;

    float pm[NH];
#pragma unroll
    for (int h = 0; h < NH; h++) pm[h] = -1e30f;
    for (int j = lane; j < deg; j += 64) {
        int e = eid[beg + j];
        const float* ap = alpha + (size_t)e * NH;
#pragma unroll
        for (int h = 0; h < NH; h++) pm[h] = fmaxf(pm[h], ap[h]);
    }
#pragma unroll
    for (int h = 0; h < NH; h++)
#pragma unroll
        for (int o = 1; o < 64; o <<= 1)
            pm[h] = fmaxf(pm[h], __shfl_xor(pm[h], o));

    float ps[NH];
    float px[NH][7];
#pragma unroll
    for (int h = 0; h < NH; h++) {
        ps[h] = 0.f;
#pragma unroll
        for (int k = 0; k < 7; k++) px[h][k] = 0.f;
    }
    for (int j = lane; j < deg; j += 64) {
        int e = eid[beg + j];
        int s = (e < N_EDGES) ? src[e] : (e - N_EDGES);
        float xv[7];
#pragma unroll
        for (int k = 0; k < 7; k++) xv[k] = x[s * 7 + k];
        const float* ap = alpha + (size_t)e * NH;
#pragma unroll
        for (int h = 0; h < NH; h++) {
            float p = __expf(ap[h] - pm[h]);
            ps[h] += p;
#pragma unroll
            for (int k = 0; k < 7; k++) px[h][k] += p * xv[k];
        }
    }
#pragma unroll
    for (int h = 0; h < NH; h++) {
#pragma unroll
        for (int o = 1; o < 64; o <<= 1) ps[h] += __shfl_xor(ps[h], o);
#pragma unroll
        for (int k = 0; k < 7; k++)
#pragma unroll
            for (int o = 1; o < 64; o <<= 1) px[h][k] += __shfl_xor(px[h][k], o);
    }
    float val = 0.f;
#pragma unroll
    for (int h = 0; h < NH; h++)
#pragma unroll
        for (int k = 0; k < 7; k++)
            if (lane == h * 7 + k) val = px[h][k] / ps[h];
    if (lane < 56) xbar[(size_t)n * 56 + lane] = val;
}

// ---------------------------------------------------------------- xbar moments
__global__ __launch_bounds__(256) void k_xmom(
    const float* __restrict__ xbar, float* __restrict__ mom)
{
    int h = blockIdx.x & 7, chunk = blockIdx.x >> 3;
    int tid = threadIdx.x, lane = tid & 63;
    float mu[7], S[49];
#pragma unroll
    for (int k = 0; k < 7; k++) mu[k] = 0.f;
#pragma unroll
    for (int k = 0; k < 49; k++) S[k] = 0.f;
    for (int i = 0; i < 8; i++) {
        int n = chunk * 2048 + i * 256 + tid;
        const float* xb = xbar + (size_t)n * 56 + h * 7;
        float xv[7];
#pragma unroll
        for (int k = 0; k < 7; k++) xv[k] = xb[k];
#pragma unroll
        for (int k = 0; k < 7; k++) {
            mu[k] += xv[k];
#pragma unroll
            for (int kk = 0; kk < 7; kk++) S[k * 7 + kk] += xv[k] * xv[kk];
        }
    }
#pragma unroll
    for (int o = 1; o < 64; o <<= 1) {
#pragma unroll
        for (int k = 0; k < 7; k++) mu[k] += __shfl_xor(mu[k], o);
#pragma unroll
        for (int k = 0; k < 49; k++) S[k] += __shfl_xor(S[k], o);
    }
    if (lane == 0) {
        float* mh = mom + h * 56;
#pragma unroll
        for (int k = 0; k < 7; k++) atomicAdd(&mh[k], mu[k]);
#pragma unroll
        for (int k = 0; k < 49; k++) atomicAdd(&mh[7 + k], S[k]);
    }
}

__global__ __launch_bounds__(256) void k_bn1_prep(
    const float* __restrict__ mom, const float* __restrict__ Wl,
    const float* __restrict__ bl, const float* __restrict__ gat_b,
    const float* __restrict__ g, const float* __restrict__ b,
    float* __restrict__ scale, float* __restrict__ shift)
{
    int f = blockIdx.x * 256 + threadIdx.x;
    if (f >= HC) return;
    int h = f / CHD;
    const float* mh = mom + h * 56;
    const float inv = 1.f / (float)N_NODES;
    float m[7], w[7];
#pragma unroll
    for (int k = 0; k < 7; k++) {
        m[k] = mh[k] * inv;
        w[k] = Wl[k * HC + f];
    }
    float mean = bl[f] + gat_b[f];
#pragma unroll
    for (int k = 0; k < 7; k++) mean += w[k] * m[k];
    float var = 0.f;
#pragma unroll
    for (int k = 0; k < 7; k++)
#pragma unroll
        for (int kk = 0; kk < 7; kk++)
            var += w[k] * w[kk] * (mh[7 + k * 7 + kk] * inv - m[k] * m[kk]);
    var = fmaxf(var, 0.f);
    float sc = g[f] * rsqrtf(var + BN_EPS);
    scale[f] = sc;
    shift[f] = b[f] - mean * sc;
}

// projection + BN1 + lrelu
__global__ __launch_bounds__(256) void k_project_bn(
    const float* __restrict__ xbar, const float* __restrict__ Wl,
    const float* __restrict__ bl, const float* __restrict__ gat_b,
    const float* __restrict__ scale, const float* __restrict__ shift,
    ushort_t* __restrict__ hout)
{
    __shared__ float xs[56];
    int n = blockIdx.x, tid = threadIdx.x;
    if (tid < 56) xs[tid] = xbar[(size_t)n * 56 + tid];
    __syncthreads();
    if (tid >= 200) return;
    int f0 = tid * 8;
    int h = f0 / CHD;
    float xb[7];
#pragma unroll
    for (int k = 0; k < 7; k++) xb[k] = xs[h * 7 + k];
    float acc[8];
    {
        float4 b0 = *(const float4*)(bl + f0), b1 = *(const float4*)(bl + f0 + 4);
        float4 g0 = *(const float4*)(gat_b + f0), g1 = *(const float4*)(gat_b + f0 + 4);
        acc[0] = b0.x + g0.x; acc[1] = b0.y + g0.y; acc[2] = b0.z + g0.z; acc[3] = b0.w + g0.w;
        acc[4] = b1.x + g1.x; acc[5] = b1.y + g1.y; acc[6] = b1.z + g1.z; acc[7] = b1.w + g1.w;
    }
#pragma unroll
    for (int k = 0; k < 7; k++) {
        float4 w0 = *(const float4*)(Wl + k * HC + f0);
        float4 w1 = *(const float4*)(Wl + k * HC + f0 + 4);
        acc[0] += xb[k] * w0.x; acc[1] += xb[k] * w0.y;
        acc[2] += xb[k] * w0.z; acc[3] += xb[k] * w0.w;
        acc[4] += xb[k] * w1.x; acc[5] += xb[k] * w1.y;
        acc[6] += xb[k] * w1.z; acc[7] += xb[k] * w1.w;
    }
    float4 s0 = *(const float4*)(scale + f0), s1 = *(const float4*)(scale + f0 + 4);
    float4 h0 = *(const float4*)(shift + f0), h1 = *(const float4*)(shift + f0 + 4);
    float sc[8] = {s0.x, s0.y, s0.z, s0.w, s1.x, s1.y, s1.z, s1.w};
    float sh[8] = {h0.x, h0.y, h0.z, h0.w, h1.x, h1.y, h1.z, h1.w};
    ushort_t o[8];
#pragma unroll
    for (int i = 0; i < 8; i++) {
        float v = acc[i] * sc[i] + sh[i];
        v = (v >= 0.f) ? v : 0.01f * v;
        o[i] = f2bf(v);
    }
    *(uint4*)(hout + (size_t)n * HC + f0) = *(uint4*)o;
}

// ---------------------------------------------------------------- BN apply (vectorized bf16x8)
__global__ __launch_bounds__(256) void k_bn_apply_bb(
    const ushort_t* __restrict__ X, ushort_t* __restrict__ Y,
    const float* __restrict__ bsum, const float* __restrict__ bsq,
    const float* __restrict__ g, const float* __restrict__ b,
    int rows, int total8, int F)
{
    int idx = blockIdx.x * 256 + threadIdx.x;
    if (idx >= total8) return;
    int e0 = idx * 8;
    int f0 = e0 % F;
    float inv = 1.f / (float)rows;
    uint4 xin = *(const uint4*)(X + e0);
    ushort_t* xv = (ushort_t*)&xin;
    ushort_t o[8];
#pragma unroll
    for (int i = 0; i < 8; i += 4) {
        float4 su = *(const float4*)(bsum + f0 + i);
        float4 sq = *(const float4*)(bsq + f0 + i);
        float4 gg = *(const float4*)(g + f0 + i);
        float4 bb = *(const float4*)(b + f0 + i);
        float mu, var, sc, sh, v;
#define DO1(comp, j) \
        mu = su.comp * inv; var = sq.comp * inv - mu * mu; \
        sc = gg.comp * rsqrtf(var + BN_EPS); sh = bb.comp - mu * sc; \
        v = bf2f(xv[i + j]) * sc + sh; v = fmaxf(v, 0.f); o[i + j] = f2bf(v);
        DO1(x, 0) DO1(y, 1) DO1(z, 2) DO1(w, 3)
#undef DO1
    }
    *(uint4*)(Y + e0) = *(uint4*)o;
}

// ---------------------------------------------------------------- MFMA GEMM 128x128, BK=64
__global__ __launch_bounds__(256) void k_mgemm(
    const ushort_t* __restrict__ A, const ushort_t* __restrict__ BT,
    const float* __restrict__ bias, ushort_t* __restrict__ Cb,
    float* __restrict__ bsum, float* __restrict__ bsq,
    int K, int Nvalid, int ldc, int relu)
{
    __shared__ __align__(16) ushort_t As[128 * 64];
    __shared__ __align__(16) ushort_t Bs[128 * 64];
    int tid = threadIdx.x;
    int lane = tid & 63;
    int wid = tid >> 6;
    int wy = wid >> 1, wx = wid & 1;

    int nx = gridDim.x;
    int lin = blockIdx.y * nx + blockIdx.x;
    int xcd = lin & 7;
    int q = lin >> 3;
    int colb = q % nx;
    int rowb = (q / nx) * 8 + xcd;
    int row0 = rowb * 128, col0 = colb * 128;

    f32x4 acc[4][4];
#pragma unroll
    for (int i = 0; i < 4; i++)
#pragma unroll
        for (int j = 0; j < 4; j++) acc[i][j] = (f32x4)0.f;

    int am = lane & 15, qq = lane >> 4;
    int lr4 = qq * 4;

    const ushort_t* pA[4];
    const ushort_t* pB[4];
    char* lA[4];
    char* lB[4];
#pragma unroll
    for (int j = 0; j < 4; j++) {
        int sA = j * 256 + tid;
        int rowS = sA >> 3, cS = sA & 7;
        int srcC = (cS ^ (rowS & 7)) << 3;
        pA[j] = A  + (size_t)(row0 + rowS) * K + srcC;
        pB[j] = BT + (size_t)(col0 + rowS) * K + srcC;
        lA[j] = (char*)As + sA * 16;
        lB[j] = (char*)Bs + sA * 16;
    }

    for (int kk = 0; kk < K; kk += 64) {
        __syncthreads();
#pragma unroll
        for (int j = 0; j < 4; j++) {
            gload16(pA[j], lA[j]); pA[j] += 64;
            gload16(pB[j], lB[j]); pB[j] += 64;
        }
        __syncthreads();

#pragma unroll
        for (int t = 0; t < 2; t++) {
            int sw = ((((t << 2) | qq) ^ (am & 7)) << 3);
            s8frag a[4], b[4];
#pragma unroll
            for (int mi = 0; mi < 4; mi++)
                a[mi] = *(const s8frag*)&As[(wy * 64 + mi * 16 + am) * 64 + sw];
#pragma unroll
            for (int ni = 0; ni < 4; ni++)
                b[ni] = *(const s8frag*)&Bs[(wx * 64 + ni * 16 + am) * 64 + sw];
#pragma unroll
            for (int mi = 0; mi < 4; mi++)
#pragma unroll
                for (int ni = 0; ni < 4; ni++)
                    acc[mi][ni] = __builtin_amdgcn_mfma_f32_16x16x32_bf16(
                        a[mi], b[ni], acc[mi][ni], 0, 0, 0);
        }
    }

    int lc = am;
#pragma unroll
    for (int ni = 0; ni < 4; ni++) {
        int col = col0 + wx * 64 + ni * 16 + lc;
        bool valid = col < Nvalid;
        float bv = valid ? bias[col] : 0.f;
        float s = 0.f, q2 = 0.f;
#pragma unroll
        for (int mi = 0; mi < 4; mi++) {
#pragma unroll
            for (int r = 0; r < 4; r++) {
                int row = row0 + wy * 64 + mi * 16 + lr4 + r;
                float v = acc[mi][ni][r] + bv;
                s += v; q2 += v * v;
                float vo = relu ? fmaxf(v, 0.f) : v;
                if (valid) Cb[(size_t)row * ldc + col] = f2bf(vo);
            }
        }
        if (bsum != nullptr && valid) {
            s += __shfl_xor(s, 16);  s += __shfl_xor(s, 32);
            q2 += __shfl_xor(q2, 16); q2 += __shfl_xor(q2, 32);
            if (qq == 0) {
                atomicAdd(&bsum[col], s);
                atomicAdd(&bsq[col], q2);
            }
        }
    }
}

// ---------------------------------------------------------------- fused CNN stage (cooperative)
struct CArgs {
    const ushort_t *h3, *WpT, *c1T, *c2T, *c3T, *c4T;
    const float *bp, *cb1, *cb2, *cb3, *cb4;
    const float *g1, *be1, *g2, *be2, *g3, *be3;
    float *bnC1, *bnC2, *bnC3;
    ushort_t *pad1, *pad2, *pad3, *pad4;
    float *out;
};

__device__ __forceinline__ void gemm_tile32x64(
    const ushort_t* __restrict__ Ain, const ushort_t* __restrict__ BT,
    int K, int Csh, int linA, int row0, int col0,
    ushort_t* As, ushort_t* Bs, f32x4* acc)
{
    int tid = threadIdx.x;
    int lane = tid & 63;
    int am = lane & 15, qq = lane >> 4;
    int w = tid >> 6, wr = w >> 1, wc = w & 1;
    int Cmask = (1 << Csh) - 1;
    acc[0] = (f32x4)0.f; acc[1] = (f32x4)0.f;

    int rowSA = tid >> 3, cSA = tid & 7;
    int srcCA = (cSA ^ (rowSA & 7)) << 3;
    int pixA = row0 + rowSA;
    int bA = pixA >> 10, yA = (pixA >> 5) & 31, xA = pixA & 31;
    const ushort_t* aptr = Ain + (size_t)pixA * K + srcCA;

    int rowSB0 = tid >> 3, rowSB1 = rowSB0 + 32;
    int cSB = tid & 7;
    const ushort_t* bptr0 = BT + (size_t)(col0 + rowSB0) * K + ((cSB ^ (rowSB0 & 7)) << 3);
    const ushort_t* bptr1 = BT + (size_t)(col0 + rowSB1) * K + ((cSB ^ (rowSB1 & 7)) << 3);

    char* lA  = (char*)As + tid * 16;
    char* lB0 = (char*)Bs + tid * 16;
    char* lB1 = (char*)Bs + (tid + 256) * 16;

    for (int kk = 0; kk < K; kk += 64) {
        __syncthreads();
        if (linA) {
            gload16(aptr, lA); aptr += 64;
        } else {
            int k = kk + srcCA;
            int p = k >> Csh, ci = k & Cmask;
            int ky = p / 5, kx = p - ky * 5;
            gload16(Ain + (((size_t)((bA * 36 + yA + ky) * 36 + xA + kx) << Csh) + ci), lA);
        }
        gload16(bptr0, lB0); bptr0 += 64;
        gload16(bptr1, lB1); bptr1 += 64;
        __syncthreads();
#pragma unroll
        for (int t = 0; t < 2; t++) {
            int sw = ((((t << 2) | qq) ^ (am & 7)) << 3);
            s8frag a   = *(const s8frag*)&As[(wr * 16 + am) * 64 + sw];
            s8frag b0f = *(const s8frag*)&Bs[(wc * 32 + am) * 64 + sw];
            s8frag b1f = *(const s8frag*)&Bs[(wc * 32 + 16 + am) * 64 + sw];
            acc[0] = __builtin_amdgcn_mfma_f32_16x16x32_bf16(a, b0f, acc[0], 0, 0, 0);
            acc[1] = __builtin_amdgcn_mfma_f32_16x16x32_bf16(a, b1f, acc[1], 0, 0, 0);
        }
    }
}

__device__ __forceinline__ void stats_contrib(
    const f32x4* acc, const float* bias, int col0, float* bsum, float* bsq)
{
    int lane = threadIdx.x & 63;
    int am = lane & 15, qq = lane >> 4;
    int wc = (threadIdx.x >> 6) & 1;
#pragma unroll
    for (int ni = 0; ni < 2; ni++) {
        int col = col0 + wc * 32 + ni * 16 + am;
        float bv = bias[col];
        float s = 0.f, q2 = 0.f;
#pragma unroll
        for (int r = 0; r < 4; r++) {
            float v = acc[ni][r] + bv;
            s += v; q2 += v * v;
        }
        s += __shfl_xor(s, 16);  s += __shfl_xor(s, 32);
        q2 += __shfl_xor(q2, 16); q2 += __shfl_xor(q2, 32);
        if (qq == 0) {
            atomicAdd(&bsum[col], s);
            atomicAdd(&bsq[col], q2);
        }
    }
}

__device__ __forceinline__ void apply_write_pad(
    const f32x4* acc, const float* bias, const float* bsum, const float* bsq,
    const float* g, const float* be, int row0, int col0, int Csh, ushort_t* pad)
{
    int lane = threadIdx.x & 63;
    int am = lane & 15, qq = lane >> 4;
    int w = threadIdx.x >> 6, wr = w >> 1, wc = w & 1;
    const float inv = 1.f / 16384.f;
#pragma unroll
    for (int ni = 0; ni < 2; ni++) {
        int col = col0 + wc * 32 + ni * 16 + am;
        float mu = bsum[col] * inv;
        float var = bsq[col] * inv - mu * mu;
        float sc = g[col] * rsqrtf(var + BN_EPS);
        float sh = be[col] - mu * sc;
        float bv = bias[col];
#pragma unroll
        for (int r = 0; r < 4; r++) {
            int row = row0 + wr * 16 + qq * 4 + r;
            int bb = row >> 10, sp = row & 1023;
            int yy = sp >> 5, xx = sp & 31;
            float v = fmaxf((acc[ni][r] + bv) * sc + sh, 0.f);
            pad[((size_t)((bb * 36 + yy + 2) * 36 + xx + 2) << Csh) + col] = f2bf(v);
        }
    }
}

__global__ __launch_bounds__(256) void k_convnet(CArgs a)
{
    cg::grid_group grid = cg::this_grid();
    __shared__ __align__(16) ushort_t As[32 * 64];
    __shared__ __align__(16) ushort_t Bs[64 * 64];
    int row0 = blockIdx.x * 32;
    int lane = threadIdx.x & 63;
    int am = lane & 15, qq = lane >> 4;
    int w = threadIdx.x >> 6, wr = w >> 1, wc = w & 1;
    f32x4 acc[2], acc2[2];

    // ---- projection -> pad1 (no BN) ----
    gemm_tile32x64(a.h3, a.WpT, 1600, 6, 1, row0, 0, As, Bs, acc);
#pragma unroll
    for (int ni = 0; ni < 2; ni++) {
        int col = wc * 32 + ni * 16 + am;
        float bv = a.bp[col];
#pragma unroll
        for (int r = 0; r < 4; r++) {
            int row = row0 + wr * 16 + qq * 4 + r;
            int bb = row >> 10, sp = row & 1023;
            int yy = sp >> 5, xx = sp & 31;
            a.pad1[((size_t)((bb * 36 + yy + 2) * 36 + xx + 2) << 6) + col] = f2bf(acc[ni][r] + bv);
        }
    }
    grid.sync();

    // ---- conv1 ----
    gemm_tile32x64(a.pad1, a.c1T, 1600, 6, 0, row0, 0, As, Bs, acc);
    stats_contrib(acc, a.cb1, 0, a.bnC1, a.bnC1 + 64);
    grid.sync();
    apply_write_pad(acc, a.cb1, a.bnC1, a.bnC1 + 64, a.g1, a.be1, row0, 0, 6, a.pad2);
    grid.sync();

    // ---- conv2 (N=128: two col tiles) ----
    gemm_tile32x64(a.pad2, a.c2T, 1600, 6, 0, row0, 0,  As, Bs, acc);
    gemm_tile32x64(a.pad2, a.c2T, 1600, 6, 0, row0, 64, As, Bs, acc2);
    stats_contrib(acc,  a.cb2, 0,  a.bnC2, a.bnC2 + 128);
    stats_contrib(acc2, a.cb2, 64, a.bnC2, a.bnC2 + 128);
    grid.sync();
    apply_write_pad(acc,  a.cb2, a.bnC2, a.bnC2 + 128, a.g2, a.be2, row0, 0,  7, a.pad3);
    apply_write_pad(acc2, a.cb2, a.bnC2, a.bnC2 + 128, a.g2, a.be2, row0, 64, 7, a.pad3);
    grid.sync();

    // ---- conv3 ----
    gemm_tile32x64(a.pad3, a.c3T, 3200, 7, 0, row0, 0, As, Bs, acc);
    stats_contrib(acc, a.cb3, 0, a.bnC3, a.bnC3 + 64);
    grid.sync();
    apply_write_pad(acc, a.cb3, a.bnC3, a.bnC3 + 64, a.g3, a.be3, row0, 0, 6, a.pad4);
    grid.sync();

    // ---- conv4 -> f32 NCHW out ----
    gemm_tile32x64(a.pad4, a.c4T, 1600, 6, 0, row0, 0, As, Bs, acc);
#pragma unroll
    for (int ni = 0; ni < 2; ni++) {
        int col = wc * 32 + ni * 16 + am;
        bool valid = col < 6;
        float bv = valid ? a.cb4[col] : 0.f;
#pragma unroll
        for (int r = 0; r < 4; r++) {
            int row = row0 + wr * 16 + qq * 4 + r;
            int bb = row >> 10, sp = row & 1023;
            if (valid) a.out[(size_t)((bb * 6 + col) << 10) + sp] = acc[ni][r] + bv;
        }
    }
}

// ---------------------------------------------------------------- launch
extern "C" void kernel_launch(void* const* d_in, const int* in_sizes, int n_in,
                              void* d_out, int out_size, void* d_ws, size_t ws_size,
                              hipStream_t stream)
{
    const float* x   = (const float*)d_in[0];
    const float* ea  = (const float*)d_in[1];
    const float* Wl  = (const float*)d_in[2];
    const float* bl  = (const float*)d_in[3];
    const float* Wr  = (const float*)d_in[4];
    const float* br  = (const float*)d_in[5];
    const float* We  = (const float*)d_in[6];
    const float* att = (const float*)d_in[7];
    const float* gat_b = (const float*)d_in[8];
    const float* bn1_g = (const float*)d_in[9];
    const float* bn1_b = (const float*)d_in[10];
    const float* W1 = (const float*)d_in[11];
    const float* b1 = (const float*)d_in[12];
    const float* bn2_g = (const float*)d_in[13];
    const float* bn2_b = (const float*)d_in[14];
    const float* W2 = (const float*)d_in[15];
    const float* b2 = (const float*)d_in[16];
    const float* Wp = (const float*)d_in[17];
    const float* bp = (const float*)d_in[18];
    const float* cw1 = (const float*)d_in[19]; const float* cb1 = (const float*)d_in[20];
    const float* g1  = (const float*)d_in[21]; const float* be1 = (const float*)d_in[22];
    const float* cw2 = (const float*)d_in[23]; const float* cb2 = (const float*)d_in[24];
    const float* g2  = (const float*)d_in[25]; const float* be2 = (const float*)d_in[26];
    const float* cw3 = (const float*)d_in[27]; const float* cb3 = (const float*)d_in[28];
    const float* g3  = (const float*)d_in[29]; const float* be3 = (const float*)d_in[30];
    const float* cw4 = (const float*)d_in[31]; const float* cb4 = (const float*)d_in[32];
    const int* src = (const int*)d_in[33];
    const int* dst = (const int*)d_in[34];
    float* out = (float*)d_out;

    const size_t SZ_REGION = (size_t)N_NODES * HC * 4;
    const size_t HALF = SZ_REGION / 2;
    char* ws = (char*)d_ws;
    char* regA = ws;
    char* regB = regA + SZ_REGION;
    char* wbase = regB + SZ_REGION;
    ushort_t* W1T  = (ushort_t*)wbase;
    ushort_t* W2T  = W1T + (size_t)1664 * 1600;
    ushort_t* WpT  = W2T + (size_t)1664 * 1600;
    ushort_t* c1T  = WpT + (size_t)128 * 1600;
    ushort_t* c2T  = c1T + (size_t)128 * 1600;
    ushort_t* c3T  = c2T + (size_t)128 * 1600;
    ushort_t* c4T  = c3T + (size_t)128 * 3200;
    ushort_t* G16  = c4T + (size_t)128 * 1600;
    float* att16   = (float*)(G16 + (size_t)1664 * 32);
    float* alpha   = att16 + 1664 + 64;
    float* xbar    = alpha + (size_t)EN_TOT * NH;
    float* bn_sc   = xbar + (size_t)N_NODES * 56;
    float* bn_sh   = bn_sc + HC;
    int*   cnt    = (int*)(bn_sh + HC + 64);
    float* ea_sum = (float*)(cnt + N_NODES);
    float* mom    = ea_sum + 16;
    float* bnG1   = mom + 448;
    float* bnC1   = bnG1 + 3200;
    float* bnC2   = bnC1 + 256;
    float* bnC3   = bnC2 + 256;
    const size_t ZBYTES = (char*)(bnC3 + 256) - (char*)cnt;
    int* offs = (int*)(bnC3 + 256 + 16);
    int* eid  = offs + N_NODES + 1 + 63;

    ushort_t* abuf16  = (ushort_t*)regA;
    ushort_t* a2buf16 = (ushort_t*)(regA + HALF);
    ushort_t* pad1 = (ushort_t*)regA;
    ushort_t* pad2 = (ushort_t*)(regA + (4u << 20));
    ushort_t* pad3 = (ushort_t*)(regA + (8u << 20));
    ushort_t* pad4 = (ushort_t*)(regA + (14u << 20));
    ushort_t* g1b16   = (ushort_t*)regB;
    ushort_t* h3_16   = (ushort_t*)regB;

    // ---- merged weight prep (one launch) ----
    k_prep<<<9407, 256, 0, stream>>>(W1, W2, Wp, cw1, cw2, cw3, cw4,
                                     Wl, bl, Wr, br, We, att,
                                     W1T, W2T, WpT, c1T, c2T, c3T, c4T, G16, att16);

    // ---- zero scratch, CSR, alpha, aggregate ----
    hipMemsetAsync(cnt, 0, ZBYTES, stream);
    k_count<<<EN_TOT / 256, 256, 0, stream>>>(dst, ea, cnt, ea_sum);
    k_scan<<<1, 256, 0, stream>>>(cnt, offs);
    k_fill<<<EN_TOT / 256, 256, 0, stream>>>(dst, offs, cnt, eid);
    k_alpha_mm<<<EN_TOT / 64, 256, 0, stream>>>(x, ea, ea_sum, src, dst, G16, att16, alpha);
    k_agg_x<<<N_NODES / 4, 256, 0, stream>>>(x, alpha, offs, eid, src, xbar);

    // ---- analytic BN1 + fused projection/lrelu ----
    k_xmom<<<64, 256, 0, stream>>>(xbar, mom);
    k_bn1_prep<<<7, 256, 0, stream>>>(mom, Wl, bl, gat_b, bn1_g, bn1_b, bn_sc, bn_sh);
    k_project_bn<<<N_NODES, 256, 0, stream>>>(xbar, Wl, bl, gat_b, bn_sc, bn_sh, abuf16);

    // ---- GEMM1 (fused BN2 stats) -> bn-apply -> GEMM2 ----
    k_mgemm<<<dim3(13, 128), 256, 0, stream>>>(abuf16, W1T, b1, g1b16,
                                               bnG1, bnG1 + 1600, 1600, 1600, 1600, 0);
    k_bn_apply_bb<<<(N_NODES * GCN / 8) / 256, 256, 0, stream>>>(g1b16, a2buf16,
                                                                 bnG1, bnG1 + 1600, bn2_g, bn2_b,
                                                                 N_NODES, N_NODES * GCN / 8, GCN);
    k_mgemm<<<dim3(13, 128), 256, 0, stream>>>(a2buf16, W2T, b2, h3_16,
                                               (float*)nullptr, (float*)nullptr, 1600, 1600, 1600, 1);

    // ---- zero padded conv buffers ----
    hipMemsetAsync(regA, 0, (size_t)17 << 20, stream);

    // ---- fused CNN stage (cooperative, 512 blocks co-resident) ----
    CArgs ca;
    ca.h3 = h3_16; ca.WpT = WpT; ca.c1T = c1T; ca.c2T = c2T; ca.c3T = c3T; ca.c4T = c4T;
    ca.bp = bp; ca.cb1 = cb1; ca.cb2 = cb2; ca.cb3 = cb3; ca.cb4 = cb4;
    ca.g1 = g1; ca.be1 = be1; ca.g2 = g2; ca.be2 = be2; ca.g3 = g3; ca.be3 = be3;
    ca.bnC1 = bnC1; ca.bnC2 = bnC2; ca.bnC3 = bnC3;
    ca.pad1 = pad1; ca.pad2 = pad2; ca.pad3 = pad3; ca.pad4 = pad4;
    ca.out = out;
    void* kargs[] = { (void*)&ca };
    hipLaunchCooperativeKernel((const void*)k_convnet, dim3(512), dim3(256), kargs, 0, stream);

    (void)in_sizes; (void)n_in; (void)out_size; (void)ws_size;
}

// Round 13
// 826.222 us; speedup vs baseline: 1.4950x; 1.4950x over previous
//
#include <hip/hip_runtime.h>
#include <cstdint>
#include <cstddef>

#define N_NODES 16384
#define N_EDGES 65536
#define EN_TOT  (N_EDGES + N_NODES)
#define FIN 7
#define HC 1600
#define NH 8
#define CHD 200
#define GCN 1600
#define CNN 64
#define BATCH 16
#define BN_EPS 1e-5f

typedef unsigned short ushort_t;
typedef __attribute__((ext_vector_type(8))) short s8frag;
typedef __attribute__((ext_vector_type(4))) float f32x4;

__device__ __forceinline__ ushort_t f2bf(float f) {
    unsigned u = __float_as_uint(f);
    unsigned r = (u + 0x7FFFu + ((u >> 16) & 1u)) >> 16;
    return (ushort_t)r;
}
__device__ __forceinline__ float bf2f(ushort_t u) {
    return __uint_as_float(((unsigned)u) << 16);
}

__device__ __forceinline__ void gload16(const void* g, void* l) {
    __builtin_amdgcn_global_load_lds((const __attribute__((address_space(1))) void*)g,
                                     (__attribute__((address_space(3))) void*)l, 16, 0, 0);
}

#define SWZ_KOFF(tid) ((((tid) & 3) ^ (((tid) >> 3) & 3)) << 3)
#define SWZ_AQ(lane, am) (((((lane) >> 4) ^ (((am) >> 1) & 3)) << 3))

// ---------------------------------------------------------------- GAT prep
__global__ __launch_bounds__(256) void k_count(
    const int* __restrict__ dst, const float* __restrict__ ea,
    int* __restrict__ cnt, float* __restrict__ ea_sum)
{
    int e = blockIdx.x * 256 + threadIdx.x;
    int d = (e < N_EDGES) ? dst[e] : (e - N_EDGES);
    atomicAdd(&cnt[d], 1);
    float v = (e < N_EDGES) ? ea[e] : 0.f;
#pragma unroll
    for (int o = 1; o < 64; o <<= 1) v += __shfl_xor(v, o);
    if ((threadIdx.x & 63) == 0) atomicAdd(ea_sum, v);
}

__global__ __launch_bounds__(256) void k_scan(int* __restrict__ cnt, int* __restrict__ offs)
{
    __shared__ int part[256];
    int t = threadIdx.x;
    int base_i = t * 64;
    int s = 0;
    for (int i = 0; i < 64; i++) s += cnt[base_i + i];
    part[t] = s;
    __syncthreads();
    for (int o = 1; o < 256; o <<= 1) {
        int add = (t >= o) ? part[t - o] : 0;
        __syncthreads();
        part[t] += add;
        __syncthreads();
    }
    int run = (t == 0) ? 0 : part[t - 1];
    for (int i = 0; i < 64; i++) {
        int v = cnt[base_i + i];
        offs[base_i + i] = run;
        run += v;
        cnt[base_i + i] = 0;
    }
    if (t == 255) offs[N_NODES] = run;
}

__global__ __launch_bounds__(256) void k_fill(const int* __restrict__ dst,
    const int* __restrict__ offs, int* __restrict__ cur, int* __restrict__ eid)
{
    int e = blockIdx.x * 256 + threadIdx.x;
    if (e >= EN_TOT) return;
    int d = (e < N_EDGES) ? dst[e] : (e - N_EDGES);
    int pos = offs[d] + atomicAdd(&cur[d], 1);
    eid[pos] = e;
}

// ---------------------------------------------------------------- merged weight prep
__global__ __launch_bounds__(256) void k_prep(
    const float* __restrict__ W1, const float* __restrict__ W2, const float* __restrict__ Wp,
    const float* __restrict__ cw1, const float* __restrict__ cw2,
    const float* __restrict__ cw3, const float* __restrict__ cw4,
    const float* __restrict__ Wl, const float* __restrict__ bl,
    const float* __restrict__ Wr, const float* __restrict__ br,
    const float* __restrict__ We, const float* __restrict__ att,
    ushort_t* __restrict__ W1T, ushort_t* __restrict__ W2T, ushort_t* __restrict__ WpT,
    ushort_t* __restrict__ c1T, ushort_t* __restrict__ c2T,
    ushort_t* __restrict__ c3T, ushort_t* __restrict__ c4T,
    ushort_t* __restrict__ G, float* __restrict__ att16)
{
    __shared__ float t[32][33];
    int lb = blockIdx.x;
    int tid = threadIdx.x;
    if (lb < 5400) {
        const float* W; ushort_t* BT; int Ndim, bx, by;
        if (lb < 2600)      { W = W1; BT = W1T; Ndim = 1600; bx = lb % 52; by = lb / 52; }
        else if (lb < 5200) { W = W2; BT = W2T; Ndim = 1600; int l = lb - 2600; bx = l % 52; by = l / 52; }
        else                { W = Wp; BT = WpT; Ndim = 64;   int l = lb - 5200; bx = l % 4;  by = l / 4; }
        int tx = tid & 31, ty = tid >> 5;
        int n0 = bx * 32, k0 = by * 32;
#pragma unroll
        for (int i = 0; i < 4; i++)
            t[ty + i * 8][tx] = (n0 + tx < Ndim)
                ? W[(size_t)(k0 + ty + i * 8) * Ndim + n0 + tx] : 0.f;
        __syncthreads();
#pragma unroll
        for (int i = 0; i < 4; i++)
            BT[(size_t)(n0 + ty + i * 8) * 1600 + k0 + tx] = f2bf(t[tx][ty + i * 8]);
    } else if (lb < 9400) {
        int idx = (lb - 5400) * 256 + tid;
        const int R1 = 128 * 1600, R2 = 128 * 1600, R3 = 128 * 3200;
        const float* w; ushort_t* o; int local, K, Cin, Cout;
        if (idx < R1)                { w = cw1; o = c1T; local = idx; K = 1600; Cin = 64;  Cout = 64; }
        else if (idx < R1 + R2)      { w = cw2; o = c2T; local = idx - R1; K = 1600; Cin = 64; Cout = 128; }
        else if (idx < R1 + R2 + R3) { w = cw3; o = c3T; local = idx - R1 - R2; K = 3200; Cin = 128; Cout = 64; }
        else                         { w = cw4; o = c4T; local = idx - R1 - R2 - R3; K = 1600; Cin = 64; Cout = 6; }
        int co = local / K;
        int k = local - co * K;
        int p = k / Cin, ci = k - p * Cin;
        o[local] = (co < Cout) ? f2bf(w[(size_t)(co * Cin + ci) * 25 + p]) : (ushort_t)0;
    } else {
        int cp = (lb - 9400) * 256 + tid;
        if (cp < 8 * 208) {
            int h = cp / 208, j = cp - h * 208;
            ushort_t v[32];
#pragma unroll
            for (int k = 0; k < 32; k++) v[k] = 0;
            float av = 0.f;
            if (j < 200) {
                int c = h * 200 + j;
#pragma unroll
                for (int k = 0; k < 7; k++) v[k]     = f2bf(Wl[k * HC + c]);
#pragma unroll
                for (int k = 0; k < 7; k++) v[7 + k] = f2bf(Wr[k * HC + c]);
                v[14] = f2bf(We[c]);
                v[15] = f2bf(bl[c] + br[c]);
                av = att[h * CHD + j];
            }
            uint4* dst4 = (uint4*)(G + (size_t)cp * 32);
#pragma unroll
            for (int i = 0; i < 4; i++) dst4[i] = ((uint4*)v)[i];
            att16[cp] = av;
        }
    }
}

// ---------------------------------------------------------------- MFMA alpha
__global__ __launch_bounds__(256) void k_alpha_mm(
    const float* __restrict__ x, const float* __restrict__ edge_attr,
    const float* __restrict__ ea_sum, const int* __restrict__ src,
    const int* __restrict__ dst, const ushort_t* __restrict__ G,
    const float* __restrict__ att16, float* __restrict__ alpha)
{
    __shared__ ushort_t Fs[64 * 32];
    int tid = threadIdx.x;
    int lane = tid & 63, w = tid >> 6;
    int e0 = blockIdx.x * 64;
    float eam = ea_sum[0] * (1.f / (float)N_EDGES);

#define FSLOT(j, k) ((j) * 32 + ((((k) >> 3) ^ (((j) >> 1) & 3)) << 3) + ((k) & 7))
    for (int i = tid; i < 64 * 16; i += 256) {
        int j = i >> 4, k = (i & 15) + 16;
        Fs[FSLOT(j, k)] = 0;
    }
    {
        int j = tid >> 2, part = tid & 3;
        int e = e0 + j;
        int s, d; float ea;
        if (e < N_EDGES) { s = src[e]; d = dst[e]; ea = edge_attr[e]; }
        else             { s = e - N_EDGES; d = s; ea = eam; }
        if (part == 0) {
#pragma unroll
            for (int k = 0; k < 4; k++) Fs[FSLOT(j, k)] = f2bf(x[s * 7 + k]);
        } else if (part == 1) {
#pragma unroll
            for (int k = 4; k < 7; k++) Fs[FSLOT(j, k)] = f2bf(x[s * 7 + k]);
            Fs[FSLOT(j, 7)] = f2bf(x[d * 7 + 0]);
        } else if (part == 2) {
#pragma unroll
            for (int k = 1; k < 5; k++) Fs[FSLOT(j, 7 + k)] = f2bf(x[d * 7 + k]);
        } else {
            Fs[FSLOT(j, 12)] = f2bf(x[d * 7 + 5]);
            Fs[FSLOT(j, 13)] = f2bf(x[d * 7 + 6]);
            Fs[FSLOT(j, 14)] = f2bf(ea);
            Fs[FSLOT(j, 15)] = f2bf(1.0f);
        }
    }
#undef FSLOT
    __syncthreads();

    int am = lane & 15;
    int aq = (lane >> 4) * 8;
    s8frag afrag = *(const s8frag*)&Fs[(w * 16 + am) * 32 + SWZ_AQ(lane, am)];
    int lr4 = (lane >> 4) * 4;
    int ew = e0 + w * 16;
#pragma unroll
    for (int h = 0; h < NH; h++) {
        f32x4 hacc = (f32x4)0.f;
        int colbase = h * 208;
#pragma unroll
        for (int t = 0; t < 13; t++) {
            int cb = colbase + t * 16;
            s8frag bfrag = *(const s8frag*)(G + ((size_t)(cb + am) * 32 + aq));
            f32x4 z = (f32x4)0.f;
            f32x4 p = __builtin_amdgcn_mfma_f32_16x16x32_bf16(afrag, bfrag, z, 0, 0, 0);
            float attv = att16[cb + am];
#pragma unroll
            for (int r = 0; r < 4; r++) {
                float v = p[r];
                v = (v >= 0.f) ? v : 0.2f * v;
                hacc[r] += v * attv;
            }
        }
#pragma unroll
        for (int o = 1; o <= 8; o <<= 1) {
#pragma unroll
            for (int r = 0; r < 4; r++) hacc[r] += __shfl_xor(hacc[r], o);
        }
        if (am == 0) {
#pragma unroll
            for (int r = 0; r < 4; r++)
                alpha[(size_t)(ew + lr4 + r) * NH + h] = hacc[r];
        }
    }
}

// ---------------------------------------------------------------- softmax + 7-dim aggregation
__global__ __launch_bounds__(256) void k_agg_x(
    const float* __restrict__ x, const float* __restrict__ alpha,
    const int* __restrict__ offs, const int* __restrict__ eid,
    const int* __restrict__ src, float* __restrict__ xbar)
{
    int n = blockIdx.x * 4 + (threadIdx.x >> 6);
    int lane = threadIdx.x & 63;
    int beg = offs[n], deg = offs[n + 1] - beg;

    float pm[NH];
#pragma unroll
    for (int h = 0; h < NH; h++) pm[h] = -1e30f;
    for (int j = lane; j < deg; j += 64) {
        int e = eid[beg + j];
        const float* ap = alpha + (size_t)e * NH;
#pragma unroll
        for (int h = 0; h < NH; h++) pm[h] = fmaxf(pm[h], ap[h]);
    }
#pragma unroll
    for (int h = 0; h < NH; h++)
#pragma unroll
        for (int o = 1; o < 64; o <<= 1)
            pm[h] = fmaxf(pm[h], __shfl_xor(pm[h], o));

    float ps[NH];
    float px[NH][7];
#pragma unroll
    for (int h = 0; h < NH; h++) {
        ps[h] = 0.f;
#pragma unroll
        for (int k = 0; k < 7; k++) px[h][k] = 0.f;
    }
    for (int j = lane; j < deg; j += 64) {
        int e = eid[beg + j];
        int s = (e < N_EDGES) ? src[e] : (e - N_EDGES);
        float xv[7];
#pragma unroll
        for (int k = 0; k < 7; k++) xv[k] = x[s * 7 + k];
        const float* ap = alpha + (size_t)e * NH;
#pragma unroll
        for (int h = 0; h < NH; h++) {
            float p = __expf(ap[h] - pm[h]);
            ps[h] += p;
#pragma unroll
            for (int k = 0; k < 7; k++) px[h][k] += p * xv[k];
        }
    }
#pragma unroll
    for (int h = 0; h < NH; h++) {
#pragma unroll
        for (int o = 1; o < 64; o <<= 1) ps[h] += __shfl_xor(ps[h], o);
#pragma unroll
        for (int k = 0; k < 7; k++)
#pragma unroll
            for (int o = 1; o < 64; o <<= 1) px[h][k] += __shfl_xor(px[h][k], o);
    }
    float val = 0.f;
#pragma unroll
    for (int h = 0; h < NH; h++)
#pragma unroll
        for (int k = 0; k < 7; k++)
            if (lane == h * 7 + k) val = px[h][k] / ps[h];
    if (lane < 56) xbar[(size_t)n * 56 + lane] = val;
}

// ---------------------------------------------------------------- xbar moments
__global__ __launch_bounds__(256) void k_xmom(
    const float* __restrict__ xbar, float* __restrict__ mom)
{
    int h = blockIdx.x & 7, chunk = blockIdx.x >> 3;
    int tid = threadIdx.x, lane = tid & 63;
    float mu[7], S[49];
#pragma unroll
    for (int k = 0; k < 7; k++) mu[k] = 0.f;
#pragma unroll
    for (int k = 0; k < 49; k++) S[k] = 0.f;
    for (int i = 0; i < 8; i++) {
        int n = chunk * 2048 + i * 256 + tid;
        const float* xb = xbar + (size_t)n * 56 + h * 7;
        float xv[7];
#pragma unroll
        for (int k = 0; k < 7; k++) xv[k] = xb[k];
#pragma unroll
        for (int k = 0; k < 7; k++) {
            mu[k] += xv[k];
#pragma unroll
            for (int kk = 0; kk < 7; kk++) S[k * 7 + kk] += xv[k] * xv[kk];
        }
    }
#pragma unroll
    for (int o = 1; o < 64; o <<= 1) {
#pragma unroll
        for (int k = 0; k < 7; k++) mu[k] += __shfl_xor(mu[k], o);
#pragma unroll
        for (int k = 0; k < 49; k++) S[k] += __shfl_xor(S[k], o);
    }
    if (lane == 0) {
        float* mh = mom + h * 56;
#pragma unroll
        for (int k = 0; k < 7; k++) atomicAdd(&mh[k], mu[k]);
#pragma unroll
        for (int k = 0; k < 49; k++) atomicAdd(&mh[7 + k], S[k]);
    }
}

__global__ __launch_bounds__(256) void k_bn1_prep(
    const float* __restrict__ mom, const float* __restrict__ Wl,
    const float* __restrict__ bl, const float* __restrict__ gat_b,
    const float* __restrict__ g, const float* __restrict__ b,
    float* __restrict__ scale, float* __restrict__ shift)
{
    int f = blockIdx.x * 256 + threadIdx.x;
    if (f >= HC) return;
    int h = f / CHD;
    const float* mh = mom + h * 56;
    const float inv = 1.f / (float)N_NODES;
    float m[7], w[7];
#pragma unroll
    for (int k = 0; k < 7; k++) {
        m[k] = mh[k] * inv;
        w[k] = Wl[k * HC + f];
    }
    float mean = bl[f] + gat_b[f];
#pragma unroll
    for (int k = 0; k < 7; k++) mean += w[k] * m[k];
    float var = 0.f;
#pragma unroll
    for (int k = 0; k < 7; k++)
#pragma unroll
        for (int kk = 0; kk < 7; kk++)
            var += w[k] * w[kk] * (mh[7 + k * 7 + kk] * inv - m[k] * m[kk]);
    var = fmaxf(var, 0.f);
    float sc = g[f] * rsqrtf(var + BN_EPS);
    scale[f] = sc;
    shift[f] = b[f] - mean * sc;
}

// projection + BN1 + lrelu: 8 nodes per block (Wl stays L1/L2-hot across nodes)
__global__ __launch_bounds__(256) void k_project_bn(
    const float* __restrict__ xbar, const float* __restrict__ Wl,
    const float* __restrict__ bl, const float* __restrict__ gat_b,
    const float* __restrict__ scale, const float* __restrict__ shift,
    ushort_t* __restrict__ hout)
{
    __shared__ float xs[8 * 56];
    int n0 = blockIdx.x * 8, tid = threadIdx.x;
    for (int i = tid; i < 8 * 56; i += 256) xs[i] = xbar[(size_t)n0 * 56 + i];
    __syncthreads();
    for (int o = tid; o < 8 * 200; o += 256) {
        int nloc = o / 200;
        int gidx = o - nloc * 200;
        int f0 = gidx * 8;
        int h = f0 / CHD;
        float xb[7];
#pragma unroll
        for (int k = 0; k < 7; k++) xb[k] = xs[nloc * 56 + h * 7 + k];
        float acc[8];
        {
            float4 b0 = *(const float4*)(bl + f0), b1 = *(const float4*)(bl + f0 + 4);
            float4 g0 = *(const float4*)(gat_b + f0), g1 = *(const float4*)(gat_b + f0 + 4);
            acc[0] = b0.x + g0.x; acc[1] = b0.y + g0.y; acc[2] = b0.z + g0.z; acc[3] = b0.w + g0.w;
            acc[4] = b1.x + g1.x; acc[5] = b1.y + g1.y; acc[6] = b1.z + g1.z; acc[7] = b1.w + g1.w;
        }
#pragma unroll
        for (int k = 0; k < 7; k++) {
            float4 w0 = *(const float4*)(Wl + k * HC + f0);
            float4 w1 = *(const float4*)(Wl + k * HC + f0 + 4);
            acc[0] += xb[k] * w0.x; acc[1] += xb[k] * w0.y;
            acc[2] += xb[k] * w0.z; acc[3] += xb[k] * w0.w;
            acc[4] += xb[k] * w1.x; acc[5] += xb[k] * w1.y;
            acc[6] += xb[k] * w1.z; acc[7] += xb[k] * w1.w;
        }
        float4 s0 = *(const float4*)(scale + f0), s1 = *(const float4*)(scale + f0 + 4);
        float4 h0 = *(const float4*)(shift + f0), h1 = *(const float4*)(shift + f0 + 4);
        float sc[8] = {s0.x, s0.y, s0.z, s0.w, s1.x, s1.y, s1.z, s1.w};
        float sh[8] = {h0.x, h0.y, h0.z, h0.w, h1.x, h1.y, h1.z, h1.w};
        ushort_t ov[8];
#pragma unroll
        for (int i = 0; i < 8; i++) {
            float v = acc[i] * sc[i] + sh[i];
            v = (v >= 0.f) ? v : 0.01f * v;
            ov[i] = f2bf(v);
        }
        *(uint4*)(hout + (size_t)(n0 + nloc) * HC + f0) = *(uint4*)ov;
    }
}

// ---------------------------------------------------------------- BN apply (vectorized bf16x8)
__global__ __launch_bounds__(256) void k_bn_apply_bb(
    const ushort_t* __restrict__ X, ushort_t* __restrict__ Y,
    const float* __restrict__ bsum, const float* __restrict__ bsq,
    const float* __restrict__ g, const float* __restrict__ b,
    int rows, int total8, int F)
{
    int idx = blockIdx.x * 256 + threadIdx.x;
    if (idx >= total8) return;
    int e0 = idx * 8;
    int f0 = e0 % F;
    float inv = 1.f / (float)rows;
    uint4 xin = *(const uint4*)(X + e0);
    ushort_t* xv = (ushort_t*)&xin;
    ushort_t o[8];
#pragma unroll
    for (int i = 0; i < 8; i += 4) {
        float4 su = *(const float4*)(bsum + f0 + i);
        float4 sq = *(const float4*)(bsq + f0 + i);
        float4 gg = *(const float4*)(g + f0 + i);
        float4 bb = *(const float4*)(b + f0 + i);
        float mu, var, sc, sh, v;
#define DO1(comp, j) \
        mu = su.comp * inv; var = sq.comp * inv - mu * mu; \
        sc = gg.comp * rsqrtf(var + BN_EPS); sh = bb.comp - mu * sc; \
        v = bf2f(xv[i + j]) * sc + sh; v = fmaxf(v, 0.f); o[i + j] = f2bf(v);
        DO1(x, 0) DO1(y, 1) DO1(z, 2) DO1(w, 3)
#undef DO1
    }
    *(uint4*)(Y + e0) = *(uint4*)o;
}

__global__ __launch_bounds__(256) void k_bn_apply_pad(
    const ushort_t* __restrict__ X, ushort_t* __restrict__ pad,
    const float* __restrict__ bsum, const float* __restrict__ bsq,
    const float* __restrict__ g, const float* __restrict__ b,
    int total8, int Csh)
{
    int idx = blockIdx.x * 256 + threadIdx.x;
    if (idx >= total8) return;
    int e0 = idx * 8;
    int C = 1 << Csh;
    int c0 = e0 & (C - 1);
    int pix = e0 >> Csh;
    int xx = pix & 31, yy = (pix >> 5) & 31, bb2 = pix >> 10;
    float inv = 1.f / 16384.f;
    uint4 xin = *(const uint4*)(X + e0);
    ushort_t* xv = (ushort_t*)&xin;
    ushort_t o[8];
#pragma unroll
    for (int i = 0; i < 8; i += 4) {
        float4 su = *(const float4*)(bsum + c0 + i);
        float4 sq = *(const float4*)(bsq + c0 + i);
        float4 gg = *(const float4*)(g + c0 + i);
        float4 bb = *(const float4*)(b + c0 + i);
        float mu, var, sc, sh, v;
#define DO1(comp, j) \
        mu = su.comp * inv; var = sq.comp * inv - mu * mu; \
        sc = gg.comp * rsqrtf(var + BN_EPS); sh = bb.comp - mu * sc; \
        v = bf2f(xv[i + j]) * sc + sh; v = fmaxf(v, 0.f); o[i + j] = f2bf(v);
        DO1(x, 0) DO1(y, 1) DO1(z, 2) DO1(w, 3)
#undef DO1
    }
    *(uint4*)(pad + (((size_t)((bb2 * 36 + yy + 2) * 36 + xx + 2)) << Csh) + c0) = *(uint4*)o;
}

// ---------------------------------------------------------------- MFMA GEMM 128x128, BK=64
__global__ __launch_bounds__(256) void k_mgemm(
    const ushort_t* __restrict__ A, const ushort_t* __restrict__ BT,
    const float* __restrict__ bias, ushort_t* __restrict__ Cb,
    float* __restrict__ bsum, float* __restrict__ bsq,
    int K, int Nvalid, int ldc, int relu)
{
    __shared__ __align__(16) ushort_t As[128 * 64];
    __shared__ __align__(16) ushort_t Bs[128 * 64];
    int tid = threadIdx.x;
    int lane = tid & 63;
    int wid = tid >> 6;
    int wy = wid >> 1, wx = wid & 1;

    int nx = gridDim.x;
    int lin = blockIdx.y * nx + blockIdx.x;
    int xcd = lin & 7;
    int q = lin >> 3;
    int colb = q % nx;
    int rowb = (q / nx) * 8 + xcd;
    int row0 = rowb * 128, col0 = colb * 128;

    f32x4 acc[4][4];
#pragma unroll
    for (int i = 0; i < 4; i++)
#pragma unroll
        for (int j = 0; j < 4; j++) acc[i][j] = (f32x4)0.f;

    int am = lane & 15, qq = lane >> 4;
    int lr4 = qq * 4;

    const ushort_t* pA[4];
    const ushort_t* pB[4];
    char* lA[4];
    char* lB[4];
#pragma unroll
    for (int j = 0; j < 4; j++) {
        int sA = j * 256 + tid;
        int rowS = sA >> 3, cS = sA & 7;
        int srcC = (cS ^ (rowS & 7)) << 3;
        pA[j] = A  + (size_t)(row0 + rowS) * K + srcC;
        pB[j] = BT + (size_t)(col0 + rowS) * K + srcC;
        lA[j] = (char*)As + sA * 16;
        lB[j] = (char*)Bs + sA * 16;
    }

    for (int kk = 0; kk < K; kk += 64) {
        __syncthreads();
#pragma unroll
        for (int j = 0; j < 4; j++) {
            gload16(pA[j], lA[j]); pA[j] += 64;
            gload16(pB[j], lB[j]); pB[j] += 64;
        }
        __syncthreads();

#pragma unroll
        for (int t = 0; t < 2; t++) {
            int sw = ((((t << 2) | qq) ^ (am & 7)) << 3);
            s8frag a[4], b[4];
#pragma unroll
            for (int mi = 0; mi < 4; mi++)
                a[mi] = *(const s8frag*)&As[(wy * 64 + mi * 16 + am) * 64 + sw];
#pragma unroll
            for (int ni = 0; ni < 4; ni++)
                b[ni] = *(const s8frag*)&Bs[(wx * 64 + ni * 16 + am) * 64 + sw];
#pragma unroll
            for (int mi = 0; mi < 4; mi++)
#pragma unroll
                for (int ni = 0; ni < 4; ni++)
                    acc[mi][ni] = __builtin_amdgcn_mfma_f32_16x16x32_bf16(
                        a[mi], b[ni], acc[mi][ni], 0, 0, 0);
        }
    }

    int lc = am;
#pragma unroll
    for (int ni = 0; ni < 4; ni++) {
        int col = col0 + wx * 64 + ni * 16 + lc;
        bool valid = col < Nvalid;
        float bv = valid ? bias[col] : 0.f;
        float s = 0.f, q2 = 0.f;
#pragma unroll
        for (int mi = 0; mi < 4; mi++) {
#pragma unroll
            for (int r = 0; r < 4; r++) {
                int row = row0 + wy * 64 + mi * 16 + lr4 + r;
                float v = acc[mi][ni][r] + bv;
                s += v; q2 += v * v;
                float vo = relu ? fmaxf(v, 0.f) : v;
                if (valid) Cb[(size_t)row * ldc + col] = f2bf(vo);
            }
        }
        if (bsum != nullptr && valid) {
            s += __shfl_xor(s, 16);  s += __shfl_xor(s, 32);
            q2 += __shfl_xor(q2, 16); q2 += __shfl_xor(q2, 32);
            if (qq == 0) {
                atomicAdd(&bsum[col], s);
                atomicAdd(&bsq[col], q2);
            }
        }
    }
}

// ---------------------------------------------------------------- 32x64 GEMM (proj + convs), BK=64
__global__ __launch_bounds__(256) void k_cgemm3(
    const ushort_t* __restrict__ Ain, const ushort_t* __restrict__ BT,
    const float* __restrict__ bias, float* __restrict__ Cf, ushort_t* __restrict__ Cb,
    float* __restrict__ bsum, float* __restrict__ bsq,
    int K, int Csh, int Nvalid, int ldc, int out_mode, int linA)
{
    __shared__ __align__(16) ushort_t As[32 * 64];
    __shared__ __align__(16) ushort_t Bs[64 * 64];
    int tid = threadIdx.x;
    int lane = tid & 63;
    int w = tid >> 6, wr = w >> 1, wc = w & 1;
    int row0 = blockIdx.y * 32, col0 = blockIdx.x * 64;
    int Cmask = (1 << Csh) - 1;

    f32x4 acc[2];
    acc[0] = (f32x4)0.f; acc[1] = (f32x4)0.f;

    int rowSA = tid >> 3, cSA = tid & 7;
    int srcCA = (cSA ^ (rowSA & 7)) << 3;
    int pixA = row0 + rowSA;
    int bA = pixA >> 10, yA = (pixA >> 5) & 31, xA = pixA & 31;
    const ushort_t* aptr = Ain + (size_t)pixA * K + srcCA;

    int rowSB0 = tid >> 3, rowSB1 = rowSB0 + 32;
    int cSB = tid & 7;
    const ushort_t* bptr0 = BT + (size_t)(col0 + rowSB0) * K + ((cSB ^ (rowSB0 & 7)) << 3);
    const ushort_t* bptr1 = BT + (size_t)(col0 + rowSB1) * K + ((cSB ^ (rowSB1 & 7)) << 3);

    char* lA  = (char*)As + tid * 16;
    char* lB0 = (char*)Bs + tid * 16;
    char* lB1 = (char*)Bs + (tid + 256) * 16;

    int am = lane & 15, qq = lane >> 4;

    for (int kk = 0; kk < K; kk += 64) {
        __syncthreads();
        if (linA) {
            gload16(aptr, lA); aptr += 64;
        } else {
            int k = kk + srcCA;
            int p = k >> Csh;
            int ci = k & Cmask;
            int ky = p / 5, kx = p - ky * 5;
            gload16(Ain + (((size_t)((bA * 36 + yA + ky) * 36 + xA + kx) << Csh) + ci), lA);
        }
        gload16(bptr0, lB0); bptr0 += 64;
        gload16(bptr1, lB1); bptr1 += 64;
        __syncthreads();

#pragma unroll
        for (int t = 0; t < 2; t++) {
            int sw = ((((t << 2) | qq) ^ (am & 7)) << 3);
            s8frag a   = *(const s8frag*)&As[(wr * 16 + am) * 64 + sw];
            s8frag b0f = *(const s8frag*)&Bs[(wc * 32 + am) * 64 + sw];
            s8frag b1f = *(const s8frag*)&Bs[(wc * 32 + 16 + am) * 64 + sw];
            acc[0] = __builtin_amdgcn_mfma_f32_16x16x32_bf16(a, b0f, acc[0], 0, 0, 0);
            acc[1] = __builtin_amdgcn_mfma_f32_16x16x32_bf16(a, b1f, acc[1], 0, 0, 0);
        }
    }

    int lc = am, lr4 = qq * 4;
#pragma unroll
    for (int ni = 0; ni < 2; ni++) {
        int col = col0 + wc * 32 + ni * 16 + lc;
        bool valid = col < Nvalid;
        float bv = valid ? bias[col] : 0.f;
        float s = 0.f, q2 = 0.f;
#pragma unroll
        for (int r = 0; r < 4; r++) {
            int row = row0 + wr * 16 + lr4 + r;
            float v = acc[ni][r] + bv;
            s += v; q2 += v * v;
            if (valid) {
                if (out_mode == 1) {
                    Cb[(size_t)row * ldc + col] = f2bf(v);
                } else if (out_mode == 3) {
                    int bb = row >> 10, sp = row & 1023;
                    int yy = sp >> 5, xx = sp & 31;
                    Cb[((size_t)((bb * 36 + yy + 2) * 36 + xx + 2) << 6) + col] = f2bf(v);
                } else {
                    int bb = row >> 10, sp = row & 1023;
                    Cf[(size_t)((bb * 6 + col) << 10) + sp] = v;
                }
            }
        }
        if (bsum != nullptr && valid) {
            s += __shfl_xor(s, 16);  s += __shfl_xor(s, 32);
            q2 += __shfl_xor(q2, 16); q2 += __shfl_xor(q2, 32);
            if (qq == 0) {
                atomicAdd(&bsum[col], s);
                atomicAdd(&bsq[col], q2);
            }
        }
    }
}

// ---------------------------------------------------------------- launch
extern "C" void kernel_launch(void* const* d_in, const int* in_sizes, int n_in,
                              void* d_out, int out_size, void* d_ws, size_t ws_size,
                              hipStream_t stream)
{
    const float* x   = (const float*)d_in[0];
    const float* ea  = (const float*)d_in[1];
    const float* Wl  = (const float*)d_in[2];
    const float* bl  = (const float*)d_in[3];
    const float* Wr  = (const float*)d_in[4];
    const float* br  = (const float*)d_in[5];
    const float* We  = (const float*)d_in[6];
    const float* att = (const float*)d_in[7];
    const float* gat_b = (const float*)d_in[8];
    const float* bn1_g = (const float*)d_in[9];
    const float* bn1_b = (const float*)d_in[10];
    const float* W1 = (const float*)d_in[11];
    const float* b1 = (const float*)d_in[12];
    const float* bn2_g = (const float*)d_in[13];
    const float* bn2_b = (const float*)d_in[14];
    const float* W2 = (const float*)d_in[15];
    const float* b2 = (const float*)d_in[16];
    const float* Wp = (const float*)d_in[17];
    const float* bp = (const float*)d_in[18];
    const float* cw1 = (const float*)d_in[19]; const float* cb1 = (const float*)d_in[20];
    const float* g1  = (const float*)d_in[21]; const float* be1 = (const float*)d_in[22];
    const float* cw2 = (const float*)d_in[23]; const float* cb2 = (const float*)d_in[24];
    const float* g2  = (const float*)d_in[25]; const float* be2 = (const float*)d_in[26];
    const float* cw3 = (const float*)d_in[27]; const float* cb3 = (const float*)d_in[28];
    const float* g3  = (const float*)d_in[29]; const float* be3 = (const float*)d_in[30];
    const float* cw4 = (const float*)d_in[31]; const float* cb4 = (const float*)d_in[32];
    const int* src = (const int*)d_in[33];
    const int* dst = (const int*)d_in[34];
    float* out = (float*)d_out;

    const size_t SZ_REGION = (size_t)N_NODES * HC * 4;
    const size_t HALF = SZ_REGION / 2;
    char* ws = (char*)d_ws;
    char* regA = ws;
    char* regB = regA + SZ_REGION;
    char* wbase = regB + SZ_REGION;
    ushort_t* W1T  = (ushort_t*)wbase;
    ushort_t* W2T  = W1T + (size_t)1664 * 1600;
    ushort_t* WpT  = W2T + (size_t)1664 * 1600;
    ushort_t* c1T  = WpT + (size_t)128 * 1600;
    ushort_t* c2T  = c1T + (size_t)128 * 1600;
    ushort_t* c3T  = c2T + (size_t)128 * 1600;
    ushort_t* c4T  = c3T + (size_t)128 * 3200;
    ushort_t* G16  = c4T + (size_t)128 * 1600;
    float* att16   = (float*)(G16 + (size_t)1664 * 32);
    float* alpha   = att16 + 1664 + 64;
    float* xbar    = alpha + (size_t)EN_TOT * NH;
    float* bn_sc   = xbar + (size_t)N_NODES * 56;
    float* bn_sh   = bn_sc + HC;
    int*   cnt    = (int*)(bn_sh + HC + 64);
    float* ea_sum = (float*)(cnt + N_NODES);
    float* mom    = ea_sum + 16;
    float* bnG1   = mom + 448;
    float* bnC1   = bnG1 + 3200;
    float* bnC2   = bnC1 + 256;
    float* bnC3   = bnC2 + 256;
    const size_t ZBYTES = (char*)(bnC3 + 256) - (char*)cnt;
    int* offs = (int*)(bnC3 + 256 + 16);
    int* eid  = offs + N_NODES + 1 + 63;

    ushort_t* abuf16  = (ushort_t*)regA;
    ushort_t* a2buf16 = (ushort_t*)(regA + HALF);
    ushort_t* pad1 = (ushort_t*)regA;
    ushort_t* pad2 = (ushort_t*)(regA + (4u << 20));
    ushort_t* pad3 = (ushort_t*)(regA + (8u << 20));
    ushort_t* pad4 = (ushort_t*)(regA + (14u << 20));
    ushort_t* c1out = (ushort_t*)(regA + (18u << 20));
    ushort_t* c2out = (ushort_t*)(regA + (22u << 20));
    ushort_t* c3out = (ushort_t*)(regA + (27u << 20));
    ushort_t* g1b16   = (ushort_t*)regB;
    ushort_t* h3_16   = (ushort_t*)regB;

    // ---- merged weight prep ----
    k_prep<<<9407, 256, 0, stream>>>(W1, W2, Wp, cw1, cw2, cw3, cw4,
                                     Wl, bl, Wr, br, We, att,
                                     W1T, W2T, WpT, c1T, c2T, c3T, c4T, G16, att16);

    // ---- zero scratch, CSR, alpha, aggregate ----
    hipMemsetAsync(cnt, 0, ZBYTES, stream);
    k_count<<<EN_TOT / 256, 256, 0, stream>>>(dst, ea, cnt, ea_sum);
    k_scan<<<1, 256, 0, stream>>>(cnt, offs);
    k_fill<<<EN_TOT / 256, 256, 0, stream>>>(dst, offs, cnt, eid);
    k_alpha_mm<<<EN_TOT / 64, 256, 0, stream>>>(x, ea, ea_sum, src, dst, G16, att16, alpha);
    k_agg_x<<<N_NODES / 4, 256, 0, stream>>>(x, alpha, offs, eid, src, xbar);

    // ---- analytic BN1 + fused projection/lrelu ----
    k_xmom<<<64, 256, 0, stream>>>(xbar, mom);
    k_bn1_prep<<<7, 256, 0, stream>>>(mom, Wl, bl, gat_b, bn1_g, bn1_b, bn_sc, bn_sh);
    k_project_bn<<<N_NODES / 8, 256, 0, stream>>>(xbar, Wl, bl, gat_b, bn_sc, bn_sh, abuf16);

    // ---- GEMM1 (fused BN2 stats) -> bn-apply -> GEMM2 ----
    k_mgemm<<<dim3(13, 128), 256, 0, stream>>>(abuf16, W1T, b1, g1b16,
                                               bnG1, bnG1 + 1600, 1600, 1600, 1600, 0);
    k_bn_apply_bb<<<(N_NODES * GCN / 8) / 256, 256, 0, stream>>>(g1b16, a2buf16,
                                                                 bnG1, bnG1 + 1600, bn2_g, bn2_b,
                                                                 N_NODES, N_NODES * GCN / 8, GCN);
    k_mgemm<<<dim3(13, 128), 256, 0, stream>>>(a2buf16, W2T, b2, h3_16,
                                               (float*)nullptr, (float*)nullptr, 1600, 1600, 1600, 1);

    // ---- zero padded conv buffers ----
    hipMemsetAsync(regA, 0, (size_t)17 << 20, stream);

    // ---- projection -> pad1 interior ----
    k_cgemm3<<<dim3(1, 512), 256, 0, stream>>>(h3_16, WpT, bp, (float*)nullptr, pad1,
                                               (float*)nullptr, (float*)nullptr,
                                               1600, 6, 64, 64, 3, 1);
    // ---- conv1 ----
    k_cgemm3<<<dim3(1, 512), 256, 0, stream>>>(pad1, c1T, cb1, (float*)nullptr, c1out,
                                               bnC1, bnC1 + 128, 1600, 6, 64, 64, 1, 0);
    k_bn_apply_pad<<<(16384 * 64 / 8) / 256, 256, 0, stream>>>(c1out, pad2, bnC1, bnC1 + 128,
                                                               g1, be1, 16384 * 64 / 8, 6);
    // ---- conv2 ----
    k_cgemm3<<<dim3(2, 512), 256, 0, stream>>>(pad2, c2T, cb2, (float*)nullptr, c2out,
                                               bnC2, bnC2 + 128, 1600, 6, 128, 128, 1, 0);
    k_bn_apply_pad<<<(16384 * 128 / 8) / 256, 256, 0, stream>>>(c2out, pad3, bnC2, bnC2 + 128,
                                                                g2, be2, 16384 * 128 / 8, 7);
    // ---- conv3 ----
    k_cgemm3<<<dim3(1, 512), 256, 0, stream>>>(pad3, c3T, cb3, (float*)nullptr, c3out,
                                               bnC3, bnC3 + 128, 3200, 7, 64, 64, 1, 0);
    k_bn_apply_pad<<<(16384 * 64 / 8) / 256, 256, 0, stream>>>(c3out, pad4, bnC3, bnC3 + 128,
                                                               g3, be3, 16384 * 64 / 8, 6);
    // ---- conv4 -> NCHW f32 d_out ----
    k_cgemm3<<<dim3(1, 512), 256, 0, stream>>>(pad4, c4T, cb4, out, (ushort_t*)nullptr,
                                               (float*)nullptr, (float*)nullptr,
                                               1600, 6, 6, 6, 2, 0);

    (void)in_sizes; (void)n_in; (void)out_size; (void)ws_size;
}